// Round 3
// baseline (87.669 us; speedup 1.0000x reference)
//
#include <hip/hip_runtime.h>

// E[b] = sum over strict-lower pairs (i,j): decomp[b, i(i-1)/2+j] / |ci-cj|.
// B=2048, N=100, NC2=4950.
//
// R2: row-per-wave mapping. Lane's j-atoms (j=lane, j=lane+64) live in
// REGISTERS (loaded once); row atom ci is wave-uniform (3 LDS broadcast
// reads per row, amortized). Zero per-pair LDS -> kills the 8-way bank
// conflicts that dominated R1. decomp reads stay coalesced.

#define BATCH 2048
#define NATOMS 100
#define NPAIRS 4950
#define BLOCK 256
#define NWAVES (BLOCK / 64)

__global__ __launch_bounds__(BLOCK) void eij_kernel(
    const float* __restrict__ coords,   // [B, N, 3]
    const float* __restrict__ decomp,   // [B, NC2]
    float* __restrict__ out)            // [B, 1]
{
    __shared__ float sx[NATOMS], sy[NATOMS], sz[NATOMS];
    __shared__ float wave_sums[NWAVES];

    const int b = blockIdx.x;
    const int t = threadIdx.x;
    const int wave = t >> 6;
    const int lane = t & 63;

    // Stage this batch's coords into LDS (SoA).
    const float* cb = coords + (size_t)b * NATOMS * 3;
    for (int a = t; a < NATOMS; a += BLOCK) {
        sx[a] = cb[a * 3 + 0];
        sy[a] = cb[a * 3 + 1];
        sz[a] = cb[a * 3 + 2];
    }
    __syncthreads();

    // Per-lane fixed j-atoms in registers (loaded once, conflict-free:
    // lane -> consecutive banks).
    const int j1 = (lane + 64 < NATOMS) ? (lane + 64) : (NATOMS - 1); // clamp, unused lanes masked below
    const float x0 = sx[lane], y0 = sy[lane], z0 = sz[lane];
    const float x1 = sx[j1],   y1 = sy[j1],   z1 = sz[j1];

    const float* db = decomp + (size_t)b * NPAIRS;
    float acc = 0.0f;

    // Rows i = 1..99 round-robin over the 4 waves. Row i starts at
    // p = i(i-1)/2, has i entries (j = 0..i-1).
    for (int i = wave + 1; i < NATOMS; i += NWAVES) {
        const int base = i * (i - 1) / 2;        // wave-uniform -> SALU
        const float cix = sx[i];                 // broadcast LDS reads
        const float ciy = sy[i];
        const float ciz = sz[i];

        if (lane < i) {                          // chunk 0: j = lane
            const float d = db[base + lane];     // coalesced
            const float dx = cix - x0, dy = ciy - y0, dz = ciz - z0;
            acc += d * rsqrtf(dx * dx + dy * dy + dz * dz);
        }
        if (lane + 64 < i) {                     // chunk 1: j = lane+64 (rows > 64)
            const float d = db[base + 64 + lane];
            const float dx = cix - x1, dy = ciy - y1, dz = ciz - z1;
            acc += d * rsqrtf(dx * dx + dy * dy + dz * dz);
        }
    }

    // Wave-64 shuffle reduction, then cross-wave combine.
    #pragma unroll
    for (int off = 32; off > 0; off >>= 1)
        acc += __shfl_down(acc, off, 64);
    if (lane == 0) wave_sums[wave] = acc;
    __syncthreads();

    if (t == 0)
        out[b] = wave_sums[0] + wave_sums[1] + wave_sums[2] + wave_sums[3];
}

extern "C" void kernel_launch(void* const* d_in, const int* in_sizes, int n_in,
                              void* d_out, int out_size, void* d_ws, size_t ws_size,
                              hipStream_t stream) {
    const float* coords = (const float*)d_in[0];   // [2048, 100, 3]
    const float* decomp = (const float*)d_in[1];   // [2048, 4950]
    float* out = (float*)d_out;                    // [2048, 1]

    eij_kernel<<<BATCH, BLOCK, 0, stream>>>(coords, decomp, out);
}

// Round 4
// 87.110 us; speedup vs baseline: 1.0064x; 1.0064x over previous
//
#include <hip/hip_runtime.h>

// E[b] = sum over strict-lower pairs (i,j): decomp[b, i(i-1)/2+j] / |ci-cj|.
// B=2048, N=100, NC2=4950.
//
// R3: two-phase per block.
//  Phase 1: row-per-wave, coords in registers -> recip_r for all 4950 pairs
//           written densely to LDS (no global loads, conflict-free writes).
//  Phase 2: pure streaming dot product decomp . recip with float2 global
//           loads (8B-aligned for every batch) and dense ds_read_b64.

#define BATCH 2048
#define NATOMS 100
#define NPAIRS 4950
#define NF2    (NPAIRS / 2)   // 2475 float2 chunks, exact
#define BLOCK 256
#define NWAVES (BLOCK / 64)

__global__ __launch_bounds__(BLOCK) void eij_kernel(
    const float* __restrict__ coords,   // [B, N, 3]
    const float* __restrict__ decomp,   // [B, NC2]
    float* __restrict__ out)            // [B, 1]
{
    __shared__ float sx[NATOMS], sy[NATOMS], sz[NATOMS];
    __shared__ alignas(16) float recip[NPAIRS];
    __shared__ float wave_sums[NWAVES];

    const int b = blockIdx.x;
    const int t = threadIdx.x;
    const int wave = t >> 6;
    const int lane = t & 63;

    // Stage this batch's coords into LDS (SoA).
    const float* cb = coords + (size_t)b * NATOMS * 3;
    for (int a = t; a < NATOMS; a += BLOCK) {
        sx[a] = cb[a * 3 + 0];
        sy[a] = cb[a * 3 + 1];
        sz[a] = cb[a * 3 + 2];
    }
    __syncthreads();

    // Per-lane fixed j-atom coords in registers (conflict-free reads).
    const int j1 = (lane + 64 < NATOMS) ? (lane + 64) : (NATOMS - 1);
    const float x0 = sx[lane], y0 = sy[lane], z0 = sz[lane];
    const float x1 = sx[j1],   y1 = sy[j1],   z1 = sz[j1];

    // Phase 1: compute recip_r for every pair, dense LDS writes.
    // Row i (i=1..99) starts at base=i(i-1)/2, entries j=0..i-1.
    for (int i = wave + 1; i < NATOMS; i += NWAVES) {
        const int base = i * (i - 1) / 2;        // wave-uniform
        const float cix = sx[i];                 // broadcast reads
        const float ciy = sy[i];
        const float ciz = sz[i];

        if (lane < i) {
            const float dx = cix - x0, dy = ciy - y0, dz = ciz - z0;
            recip[base + lane] = rsqrtf(dx * dx + dy * dy + dz * dz);
        }
        if (lane + 64 < i) {
            const float dx = cix - x1, dy = ciy - y1, dz = ciz - z1;
            recip[base + 64 + lane] = rsqrtf(dx * dx + dy * dy + dz * dz);
        }
    }
    __syncthreads();

    // Phase 2: streaming dot product. decomp row is 8B-aligned for every b
    // (4950*4 = 19800 bytes per row, divisible by 8).
    const float2* __restrict__ d2 =
        (const float2*)(decomp + (size_t)b * NPAIRS);
    const float2* __restrict__ r2 = (const float2*)recip;

    float acc = 0.0f;
    #pragma unroll
    for (int c = 0; c < (NF2 + BLOCK - 1) / BLOCK; ++c) {
        const int idx = t + c * BLOCK;
        if (idx < NF2) {
            const float2 d = d2[idx];            // coalesced 8B global
            const float2 r = r2[idx];            // dense ds_read_b64
            acc += d.x * r.x + d.y * r.y;
        }
    }

    // Wave-64 shuffle reduction, then cross-wave combine.
    #pragma unroll
    for (int off = 32; off > 0; off >>= 1)
        acc += __shfl_down(acc, off, 64);
    if (lane == 0) wave_sums[wave] = acc;
    __syncthreads();

    if (t == 0)
        out[b] = wave_sums[0] + wave_sums[1] + wave_sums[2] + wave_sums[3];
}

extern "C" void kernel_launch(void* const* d_in, const int* in_sizes, int n_in,
                              void* d_out, int out_size, void* d_ws, size_t ws_size,
                              hipStream_t stream) {
    const float* coords = (const float*)d_in[0];   // [2048, 100, 3]
    const float* decomp = (const float*)d_in[1];   // [2048, 4950]
    float* out = (float*)d_out;                    // [2048, 1]

    eij_kernel<<<BATCH, BLOCK, 0, stream>>>(coords, decomp, out);
}

// Round 5
// 86.773 us; speedup vs baseline: 1.0103x; 1.0039x over previous
//
#include <hip/hip_runtime.h>

// E[b] = sum over strict-lower pairs (i,j): decomp[b, i(i-1)/2+j] / |ci-cj|.
// B=2048, N=100, NC2=4950.
//
// R4: lean two-phase.
//  - coords staged via aligned float4 burst (75 dwordx4, one latency hit)
//  - all 10 decomp float2 loads prefetched into registers BEFORE phase 1
//    (global latency overlaps rsqrt compute)
//  - phase 1: row-per-wave recip_r -> dense LDS
//  - phase 2: register decomp . LDS recip, branch-free tail

#define BATCH 2048
#define NATOMS 100
#define NPAIRS 4950
#define NF2    (NPAIRS / 2)        // 2475 float2, exact
#define BLOCK 256
#define NWAVES (BLOCK / 64)
#define NCHUNK ((NF2 + BLOCK - 1) / BLOCK)   // 10

__global__ __launch_bounds__(BLOCK) void eij_kernel(
    const float* __restrict__ coords,   // [B, N, 3]
    const float* __restrict__ decomp,   // [B, NC2]
    float* __restrict__ out)            // [B, 1]
{
    __shared__ alignas(16) float sc[NATOMS * 3];   // xyz interleaved
    __shared__ alignas(16) float recip[NPAIRS];
    __shared__ float wave_sums[NWAVES];

    const int b = blockIdx.x;
    const int t = threadIdx.x;
    const int wave = t >> 6;
    const int lane = t & 63;

    // --- coords staging: 300 floats = 75 float4, 16B-aligned every batch.
    const float4* __restrict__ cb4 =
        (const float4*)(coords + (size_t)b * NATOMS * 3);
    if (t < NATOMS * 3 / 4) ((float4*)sc)[t] = cb4[t];

    // --- prefetch decomp into registers (independent of phase 1).
    const float2* __restrict__ d2 =
        (const float2*)(decomp + (size_t)b * NPAIRS);
    float2 dreg[NCHUNK];
    #pragma unroll
    for (int c = 0; c < NCHUNK - 1; ++c)
        dreg[c] = d2[t + c * BLOCK];               // unconditional, in flight
    {
        const int idx = t + (NCHUNK - 1) * BLOCK;
        dreg[NCHUNK - 1] = d2[idx < NF2 ? idx : NF2 - 1];
    }

    __syncthreads();   // sc ready

    // --- per-lane fixed j-atom coords in registers.
    const int j1 = (lane + 64 < NATOMS) ? (lane + 64) : (NATOMS - 1);
    const float x0 = sc[lane * 3 + 0], y0 = sc[lane * 3 + 1], z0 = sc[lane * 3 + 2];
    const float x1 = sc[j1 * 3 + 0],   y1 = sc[j1 * 3 + 1],   z1 = sc[j1 * 3 + 2];

    // --- phase 1: recip_r for every pair, dense LDS writes.
    for (int i = wave + 1; i < NATOMS; i += NWAVES) {
        const int base = i * (i - 1) / 2;          // wave-uniform
        const float cix = sc[i * 3 + 0];           // broadcast reads
        const float ciy = sc[i * 3 + 1];
        const float ciz = sc[i * 3 + 2];

        if (lane < i) {
            const float dx = cix - x0, dy = ciy - y0, dz = ciz - z0;
            recip[base + lane] = rsqrtf(dx * dx + dy * dy + dz * dz);
        }
        if (lane + 64 < i) {
            const float dx = cix - x1, dy = ciy - y1, dz = ciz - z1;
            recip[base + 64 + lane] = rsqrtf(dx * dx + dy * dy + dz * dz);
        }
    }
    __syncthreads();   // recip ready

    // --- phase 2: register decomp . LDS recip, branch-free.
    const float2* __restrict__ r2 = (const float2*)recip;
    float acc = 0.0f;
    #pragma unroll
    for (int c = 0; c < NCHUNK - 1; ++c) {
        const float2 r = r2[t + c * BLOCK];        // dense ds_read_b64
        acc += dreg[c].x * r.x + dreg[c].y * r.y;
    }
    {
        const int idx = t + (NCHUNK - 1) * BLOCK;
        if (idx < NF2) {
            const float2 r = r2[idx];
            acc += dreg[NCHUNK - 1].x * r.x + dreg[NCHUNK - 1].y * r.y;
        }
    }

    // --- reduction.
    #pragma unroll
    for (int off = 32; off > 0; off >>= 1)
        acc += __shfl_down(acc, off, 64);
    if (lane == 0) wave_sums[wave] = acc;
    __syncthreads();

    if (t == 0)
        out[b] = wave_sums[0] + wave_sums[1] + wave_sums[2] + wave_sums[3];
}

extern "C" void kernel_launch(void* const* d_in, const int* in_sizes, int n_in,
                              void* d_out, int out_size, void* d_ws, size_t ws_size,
                              hipStream_t stream) {
    const float* coords = (const float*)d_in[0];   // [2048, 100, 3]
    const float* decomp = (const float*)d_in[1];   // [2048, 4950]
    float* out = (float*)d_out;                    // [2048, 1]

    eij_kernel<<<BATCH, BLOCK, 0, stream>>>(coords, decomp, out);
}